// Round 11
// baseline (295.365 us; speedup 1.0000x reference)
//
#include <hip/hip_runtime.h>
#include <stdint.h>

typedef __attribute__((ext_vector_type(8))) short short8;
typedef __attribute__((ext_vector_type(4))) float f32x4;
typedef __attribute__((ext_vector_type(2))) unsigned int uint2v;

#define C0 228
#define C1 111
#define C2 51
#define KP 448            // padded channels: [0,256)=b0, [256,384)=b1, [384,448)=b2
#define RS 458            // LDS row stride in bf16; 229 dwords (odd) -> conflict-free (R6: 0 conflicts)
#define NPIX 64

// ---- balanced (tile,ks) schedule: 224 chunks = 8 waves x 28 slots (R4/R9/R10-verified) ----
constexpr int A_KS[28] = {0,1,2,3,4,5,6,7,8,8,8,9,9,9,10,10,10,11,11,11,12,12,12,12,13,13,13,13};
constexpr int A_T [28] = {3,3,3,3,3,3,3,3,0,1,2,0,1,2, 0, 1, 2, 0, 1, 2, 0, 1, 2, 3, 0, 1, 2, 3};
constexpr int B_KS[28] = {0,0,1,1,2,2,3,3,4,4,5,5,6,6,7,7,8,8,9,9,10,10,11,11,12,12,13,13};
constexpr int B_T [28] = {1,2,1,2,1,2,1,2,1,2,1,2,1,2,1,2,0,2,0,2, 0, 2, 0, 2, 0, 1, 0, 1};

__host__ __device__ constexpr int tile_id(int w, int t) {
  return (w < 4) ? ((t < 3) ? (3 * w + t) : (16 + w))
                 : ((t == 0) ? (8 + w) : (t == 1) ? (16 + w) : (20 + w));
}

__device__ __forceinline__ unsigned short f2bf(float f) {
  unsigned u = __float_as_uint(f);
  u += 0x7FFFu + ((u >> 16) & 1u);          // RNE
  return (unsigned short)(u >> 16);
}
__device__ __forceinline__ float bf2f(unsigned v) {
  return __uint_as_float(v << 16);
}
__device__ __forceinline__ int out_chan(int c) {
  if (c < 228) return c;
  if (c < 256) return -1;
  if (c < 367) return 228 + (c - 256);
  if (c < 384) return -1;
  if (c < 435) return 339 + (c - 384);
  return -1;
}

// ---- prep: weights -> schedule-ordered 1KB fragment chunks + summed bias (R9/R10-verified) ----
__global__ void crf_prep(
    const float* __restrict__ w01, const float* __restrict__ w02,
    const float* __restrict__ w10, const float* __restrict__ w12,
    const float* __restrict__ w20, const float* __restrict__ w21,
    const float* __restrict__ b01, const float* __restrict__ b02,
    const float* __restrict__ b10, const float* __restrict__ b12,
    const float* __restrict__ b20, const float* __restrict__ b21,
    unsigned short* __restrict__ Wfrag, float* __restrict__ bbig) {
  int idx = blockIdx.x * 256 + threadIdx.x;     // 448 blocks -> 224*512
  if (idx < KP) {
    float bv = 0.f;
    int c = idx;
    if (c < 228)                  bv = b10[c] + b20[c];
    else if (c >= 256 && c < 367) bv = b01[c - 256] + b21[c - 256];
    else if (c >= 384 && c < 435) bv = b02[c - 384] + b12[c - 384];
    bbig[idx] = bv;
  }
  if (idx >= 224 * 512) return;
  const int ch = idx >> 9;
  const int e  = idx & 511;
  const int w  = ch / 28;
  const int s  = ch - w * 28;
  const int ks = (w < 4) ? A_KS[s] : B_KS[s];
  const int tl = (w < 4) ? A_T[s]  : B_T[s];
  const int tile = tile_id(w, tl);
  const int lane = e >> 3, el = e & 7;
  const int m = tile * 16 + (lane & 15);
  const int k = ks * 32 + (lane >> 4) * 8 + el;

  int bm, lm, bk, lk, Ck;
  bool mr, kr;
  if (m < 256)      { bm = 0; lm = m;       mr = lm < C0; }
  else if (m < 384) { bm = 1; lm = m - 256; mr = lm < C1; }
  else              { bm = 2; lm = m - 384; mr = lm < C2; }
  if (k < 256)      { bk = 0; lk = k;       Ck = C0; kr = lk < C0; }
  else if (k < 384) { bk = 1; lk = k - 256; Ck = C1; kr = lk < C1; }
  else              { bk = 2; lk = k - 384; Ck = C2; kr = lk < C2; }
  float v = 0.f;
  if (bm != bk && mr && kr) {
    const float* wp;
    if (bk == 0)      wp = (bm == 1) ? w01 : w02;
    else if (bk == 1) wp = (bm == 0) ? w10 : w12;
    else              wp = (bm == 0) ? w20 : w21;
    v = wp[lm * Ck + lk];
  }
  Wfrag[idx] = f2bf(v);
}

// ---- K-loop: Wfrag linear 1KB bursts (L2) x RS-layout LDS h fragments ----
template <int CLS>
__device__ __forceinline__ void kloop(const unsigned short (*hL)[RS],
                                      const unsigned short* __restrict__ wp,
                                      f32x4 (&acc)[4][4], int l15, int lq) {
  short8 bq[4];
  #pragma unroll
  for (int s = 0; s < 28; ++s) {
    const int ks = CLS ? B_KS[s] : A_KS[s];
    const int t  = CLS ? B_T[s]  : A_T[s];
    const bool newks = (s == 0) || (ks != (CLS ? B_KS[s - 1] : A_KS[s - 1]));
    if (newks) {
      const int kcol = ks * 32 + (lq << 3);
      #pragma unroll
      for (int n = 0; n < 4; ++n)
        bq[n] = *reinterpret_cast<const short8*>(&hL[n * 16 + l15][kcol]);
    }
    const short8 aq = *reinterpret_cast<const short8*>(wp + (s << 9));
    #pragma unroll
    for (int n = 0; n < 4; ++n)
      acc[t][n] =
          __builtin_amdgcn_mfma_f32_16x16x32_bf16(aq, bq[n], acc[t][n], 0, 0, 0);
  }
}

// ---- main: 2048 wgs x 512 thr (8 waves), 64-px tile, 2 wg/CU independent
//      barrier groups. R3-proven stage; RS=458 banking; Wfrag bursts; setprio. ----
__global__ __launch_bounds__(512, 4) void crf_main(
    const float* __restrict__ x0, const float* __restrict__ x1,
    const float* __restrict__ x2,
    const unsigned short* __restrict__ Wfrag,
    const float* __restrict__ bbig,
    const float* __restrict__ pa,
    float* __restrict__ out) {
  __shared__ unsigned short hL[NPIX][RS];   // 58624 B -> 2 wg/CU
  const int lane = threadIdx.x & 63;
  const int wave = threadIdx.x >> 6;
  const int l15 = lane & 15;
  const int lq = lane >> 4;
  const float apar = pa[0];
  const int tile = blockIdx.x;
  const int b = tile >> 10;                 // 1024 tiles per batch image
  const int pp0 = (tile & 1023) << 6;

  // ---- stage-in (R3-proven): lane = pixel; 56 scalar nt loads -> bf16 -> short8 LDS ----
  #pragma unroll
  for (int g = 0; g < 7; ++g) {
    const int c0 = (wave + g * 8) * 8;
    short8 pk;
    #pragma unroll
    for (int cc = 0; cc < 8; ++cc) {
      const int c = c0 + cc;
      float v = 0.f;
      if (c < 228)
        v = __builtin_nontemporal_load(x0 + (((size_t)(b * C0 + c)) << 16) + pp0 + lane);
      else if (c >= 256 && c < 367)
        v = __builtin_nontemporal_load(x1 + (((size_t)(b * C1 + (c - 256))) << 16) + pp0 + lane);
      else if (c >= 384 && c < 435)
        v = __builtin_nontemporal_load(x2 + (((size_t)(b * C2 + (c - 384))) << 16) + pp0 + lane);
      pk[cc] = (short)f2bf(v);
    }
    *reinterpret_cast<short8*>(&hL[lane][c0]) = pk;
  }
  __syncthreads();

  const unsigned short* wp = Wfrag + (((size_t)wave * 28) << 9) + (lane << 3);

  #pragma unroll
  for (int it = 0; it < 2; ++it) {
    f32x4 acc[4][4];
    #pragma unroll
    for (int t = 0; t < 4; ++t)
      #pragma unroll
      for (int n = 0; n < 4; ++n) acc[t][n] = (f32x4){0.f, 0.f, 0.f, 0.f};

    __builtin_amdgcn_s_setprio(1);
    if (wave < 4) kloop<0>(hL, wp, acc, l15, lq);
    else          kloop<1>(hL, wp, acc, l15, lq);
    __builtin_amdgcn_s_setprio(0);
    __syncthreads();   // kloop reads of hL complete before writeback

    if (it == 0) {
      // h1 = relu(h0 + prelu(binary + bias)); write back bf16 in place
      #pragma unroll
      for (int t = 0; t < 4; ++t) {
        if (t == 3 && wave >= 4) continue;
        const int cb = tile_id(wave, t) * 16 + (lq << 2);
        const f32x4 bias = *reinterpret_cast<const f32x4*>(bbig + cb);
        #pragma unroll
        for (int n = 0; n < 4; ++n) {
          const int p = n * 16 + l15;
          uint2v ho = *reinterpret_cast<const uint2v*>(&hL[p][cb]);
          const float hof[4] = {bf2f(ho[0] & 0xFFFFu), bf2f(ho[0] >> 16),
                                bf2f(ho[1] & 0xFFFFu), bf2f(ho[1] >> 16)};
          unsigned short nb[4];
          #pragma unroll
          for (int r = 0; r < 4; ++r) {
            float v = acc[t][n][r] + bias[r];
            float pr = (v >= 0.f) ? v : apar * v;
            nb[r] = f2bf(fmaxf(hof[r] + pr, 0.f));
          }
          uint2v pw;
          pw[0] = (unsigned)nb[0] | ((unsigned)nb[1] << 16);
          pw[1] = (unsigned)nb[2] | ((unsigned)nb[3] << 16);
          *reinterpret_cast<uint2v*>(&hL[p][cb]) = pw;
        }
      }
      __syncthreads();
    } else {
      // final: out = relu(h1 + prelu(binary + bias)) -> global fp32 (streaming)
      #pragma unroll
      for (int t = 0; t < 4; ++t) {
        if (t == 3 && wave >= 4) continue;
        const int cb = tile_id(wave, t) * 16 + (lq << 2);
        const f32x4 bias = *reinterpret_cast<const f32x4*>(bbig + cb);
        #pragma unroll
        for (int n = 0; n < 4; ++n) {
          const int p = n * 16 + l15;
          uint2v ho = *reinterpret_cast<const uint2v*>(&hL[p][cb]);
          const float hof[4] = {bf2f(ho[0] & 0xFFFFu), bf2f(ho[0] >> 16),
                                bf2f(ho[1] & 0xFFFFu), bf2f(ho[1] >> 16)};
          #pragma unroll
          for (int r = 0; r < 4; ++r) {
            const int c = cb + r;
            const int o = out_chan(c);
            float v = acc[t][n][r] + bias[r];
            float pr = (v >= 0.f) ? v : apar * v;
            float hn = fmaxf(hof[r] + pr, 0.f);
            if (o >= 0)
              __builtin_nontemporal_store(
                  hn, out + (((size_t)(b * 390 + o)) << 16) + pp0 + p);
          }
        }
      }
    }
  }
}

extern "C" void kernel_launch(void* const* d_in, const int* in_sizes, int n_in,
                              void* d_out, int out_size, void* d_ws, size_t ws_size,
                              hipStream_t stream) {
  const float* x0  = (const float*)d_in[0];
  const float* x1  = (const float*)d_in[1];
  const float* x2  = (const float*)d_in[2];
  const float* w01 = (const float*)d_in[3];
  const float* b01 = (const float*)d_in[4];
  const float* w02 = (const float*)d_in[5];
  const float* b02 = (const float*)d_in[6];
  const float* w10 = (const float*)d_in[7];
  const float* b10 = (const float*)d_in[8];
  const float* w12 = (const float*)d_in[9];
  const float* b12 = (const float*)d_in[10];
  const float* w20 = (const float*)d_in[11];
  const float* b20 = (const float*)d_in[12];
  const float* w21 = (const float*)d_in[13];
  const float* b21 = (const float*)d_in[14];
  const float* pa  = (const float*)d_in[15];

  unsigned short* Wfrag = (unsigned short*)d_ws;              // 224*512*2 = 229376 B
  float* bbig = (float*)((char*)d_ws + 229376);               // +1792 B

  crf_prep<<<dim3(448), dim3(256), 0, stream>>>(
      w01, w02, w10, w12, w20, w21, b01, b02, b10, b12, b20, b21, Wfrag, bbig);
  crf_main<<<dim3(2048), dim3(512), 0, stream>>>(x0, x1, x2, Wfrag, bbig, pa,
                                                 (float*)d_out);
}